// Round 1
// baseline (6911.227 us; speedup 1.0000x reference)
//
#include <hip/hip_runtime.h>
#include <hip/hip_bf16.h>
#include <math.h>

#define BN_ 4096
#define SN 24
#define TN 24
#define EN 128
#define HN 512
#define GN 1536
#define VN 256
#define BOW_ 1

__global__ void zero_kernel(float* __restrict__ p, int n) {
    int i = blockIdx.x * blockDim.x + threadIdx.x;
    if (i < n) p[i] = 0.0f;
}

__global__ void add_kernel(const float* __restrict__ a, const float* __restrict__ b,
                           float* __restrict__ c, int n) {
    int i = blockIdx.x * blockDim.x + threadIdx.x;
    if (i < n) c[i] = a[i] + b[i];
}

// P[mat] = emb @ W + b_input  for (Wf,src), (Wb,src), (Wd,tgt). One block per (mat,row).
__global__ void precomp_P(const float* __restrict__ src_emb, const float* __restrict__ tgt_emb,
                          const float* __restrict__ Wf, const float* __restrict__ bf,
                          const float* __restrict__ Wb, const float* __restrict__ bb,
                          const float* __restrict__ Wd, const float* __restrict__ bd,
                          float* __restrict__ Pf, float* __restrict__ Pb, float* __restrict__ Pd) {
    int mat = blockIdx.x / VN;
    int row = blockIdx.x % VN;
    const float* emb = (mat == 2) ? tgt_emb : src_emb;
    const float* W   = (mat == 0) ? Wf : (mat == 1) ? Wb : Wd;
    const float* bia = (mat == 0) ? bf : (mat == 1) ? bb : bd;
    float* P         = (mat == 0) ? Pf : (mat == 1) ? Pb : Pd;
    __shared__ float e[EN];
    for (int i = threadIdx.x; i < EN; i += blockDim.x) e[i] = emb[row * EN + i];
    __syncthreads();
    for (int c = threadIdx.x; c < GN; c += blockDim.x) {
        float s = bia[c];
#pragma unroll 8
        for (int k = 0; k < EN; k++) s += e[k] * W[k * GN + c];
        P[row * GN + c] = s;
    }
}

// One GRU step: rp = h_in @ U + b_rec, gates, h_out. Tile: 64 rows x (3 x 64) gate-cols.
// mode: 0 = enc fwd (idx = source[b][t]); 1 = enc bwd (idx = source[b][S-1-t]);
//       2 = dec (idx = t==0 ? BOW : targets[b][t-1]).
// blockIdx.z selects parameter set A (z=0) or B (z=1) so both encoder dirs run in one launch.
__global__ __launch_bounds__(256) void gru_step(
    const float* __restrict__ hA_in, float* __restrict__ hA_out,
    const float* __restrict__ UA, const float* __restrict__ brA,
    const float* __restrict__ PA, int modeA,
    const float* __restrict__ hB_in, float* __restrict__ hB_out,
    const float* __restrict__ UB, const float* __restrict__ brB,
    const float* __restrict__ PB, int modeB,
    const int* __restrict__ tok, int t) {
    const float* h_in; float* h_out; const float* U; const float* brec; const float* P; int mode;
    if (blockIdx.z == 0) { h_in = hA_in; h_out = hA_out; U = UA; brec = brA; P = PA; mode = modeA; }
    else                 { h_in = hB_in; h_out = hB_out; U = UB; brec = brB; P = PB; mode = modeB; }

    const int bm = blockIdx.x * 64;
    const int bj = blockIdx.y * 64;
    const int tid = threadIdx.x;
    const int tx = tid & 15;
    const int ty = tid >> 4;

    __shared__ __align__(16) float As[64][17];
    __shared__ __align__(16) float Bs[16][192];

    float acc[3][4][4];
#pragma unroll
    for (int g = 0; g < 3; g++)
#pragma unroll
        for (int i = 0; i < 4; i++)
#pragma unroll
            for (int j = 0; j < 4; j++) acc[g][i][j] = 0.0f;

    const int ar = tid >> 2;          // 0..63  A row
    const int ak = (tid & 3) * 4;     // 0,4,8,12 A k
    const int bk = tid >> 4;          // 0..15  B k-row
    const int bc = (tid & 15) * 4;    // 0..60  B col

    for (int k0 = 0; k0 < HN; k0 += 16) {
        float4 av = *reinterpret_cast<const float4*>(&h_in[(bm + ar) * HN + k0 + ak]);
        As[ar][ak + 0] = av.x; As[ar][ak + 1] = av.y; As[ar][ak + 2] = av.z; As[ar][ak + 3] = av.w;
#pragma unroll
        for (int g = 0; g < 3; g++) {
            float4 bv = *reinterpret_cast<const float4*>(&U[(k0 + bk) * GN + g * HN + bj + bc]);
            *reinterpret_cast<float4*>(&Bs[bk][g * 64 + bc]) = bv;
        }
        __syncthreads();
#pragma unroll
        for (int kk = 0; kk < 16; kk++) {
            float a[4];
#pragma unroll
            for (int i = 0; i < 4; i++) a[i] = As[ty * 4 + i][kk];
#pragma unroll
            for (int g = 0; g < 3; g++) {
                float4 bv = *reinterpret_cast<float4*>(&Bs[kk][g * 64 + tx * 4]);
#pragma unroll
                for (int i = 0; i < 4; i++) {
                    acc[g][i][0] += a[i] * bv.x;
                    acc[g][i][1] += a[i] * bv.y;
                    acc[g][i][2] += a[i] * bv.z;
                    acc[g][i][3] += a[i] * bv.w;
                }
            }
        }
        __syncthreads();
    }

#pragma unroll
    for (int i = 0; i < 4; i++) {
        const int row = bm + ty * 4 + i;
        int idx;
        if (mode == 2) idx = (t == 0) ? BOW_ : tok[row * TN + (t - 1)];
        else           idx = tok[row * SN + ((mode == 0) ? t : (SN - 1 - t))];
        const float* Pr = &P[idx * GN];
#pragma unroll
        for (int j = 0; j < 4; j++) {
            const int col = bj + tx * 4 + j;
            float rz = acc[0][i][j] + brec[col];
            float rr = acc[1][i][j] + brec[HN + col];
            float rh = acc[2][i][j] + brec[2 * HN + col];
            float xz = Pr[col], xr = Pr[HN + col], xh = Pr[2 * HN + col];
            float z = 1.0f / (1.0f + expf(-(xz + rz)));
            float r = 1.0f / (1.0f + expf(-(xr + rr)));
            float hh = tanhf(xh + r * rh);
            float hold = h_in[row * HN + col];
            h_out[row * HN + col] = z * hold + (1.0f - z) * hh;
        }
    }
}

// logits[:, t, :] = hd @ Wo + bo.  M=4096, N=256, K=512.
__global__ __launch_bounds__(256) void logits_kernel(const float* __restrict__ hd,
                                                     const float* __restrict__ Wo,
                                                     const float* __restrict__ bo,
                                                     float* __restrict__ out, int t) {
    const int bm = blockIdx.x * 64;
    const int bn = blockIdx.y * 64;
    const int tid = threadIdx.x;
    const int tx = tid & 15;
    const int ty = tid >> 4;

    __shared__ __align__(16) float As[64][17];
    __shared__ __align__(16) float Bs[16][64];

    float acc[4][4];
#pragma unroll
    for (int i = 0; i < 4; i++)
#pragma unroll
        for (int j = 0; j < 4; j++) acc[i][j] = 0.0f;

    const int ar = tid >> 2;
    const int ak = (tid & 3) * 4;
    const int bk = tid >> 4;
    const int bc = (tid & 15) * 4;

    for (int k0 = 0; k0 < HN; k0 += 16) {
        float4 av = *reinterpret_cast<const float4*>(&hd[(bm + ar) * HN + k0 + ak]);
        As[ar][ak + 0] = av.x; As[ar][ak + 1] = av.y; As[ar][ak + 2] = av.z; As[ar][ak + 3] = av.w;
        float4 bv = *reinterpret_cast<const float4*>(&Wo[(k0 + bk) * VN + bn + bc]);
        *reinterpret_cast<float4*>(&Bs[bk][bc]) = bv;
        __syncthreads();
#pragma unroll
        for (int kk = 0; kk < 16; kk++) {
            float a[4];
#pragma unroll
            for (int i = 0; i < 4; i++) a[i] = As[ty * 4 + i][kk];
            float4 b4 = *reinterpret_cast<float4*>(&Bs[kk][tx * 4]);
#pragma unroll
            for (int i = 0; i < 4; i++) {
                acc[i][0] += a[i] * b4.x;
                acc[i][1] += a[i] * b4.y;
                acc[i][2] += a[i] * b4.z;
                acc[i][3] += a[i] * b4.w;
            }
        }
        __syncthreads();
    }

#pragma unroll
    for (int i = 0; i < 4; i++) {
        const int row = bm + ty * 4 + i;
#pragma unroll
        for (int j = 0; j < 4; j++) {
            const int col = bn + tx * 4 + j;
            out[row * (TN * VN) + t * VN + col] = acc[i][j] + bo[col];
        }
    }
}

extern "C" void kernel_launch(void* const* d_in, const int* in_sizes, int n_in,
                              void* d_out, int out_size, void* d_ws, size_t ws_size,
                              hipStream_t stream) {
    const int* source    = (const int*)d_in[0];
    const int* targets   = (const int*)d_in[1];
    const float* src_emb = (const float*)d_in[2];
    const float* tgt_emb = (const float*)d_in[3];
    const float* Wf = (const float*)d_in[4];
    const float* Uf = (const float*)d_in[5];
    const float* bf = (const float*)d_in[6];
    const float* Wb = (const float*)d_in[7];
    const float* Ub = (const float*)d_in[8];
    const float* bb = (const float*)d_in[9];
    const float* Wd = (const float*)d_in[10];
    const float* Ud = (const float*)d_in[11];
    const float* bd = (const float*)d_in[12];
    const float* Wo = (const float*)d_in[13];
    const float* bo = (const float*)d_in[14];
    float* out = (float*)d_out;

    float* ws = (float*)d_ws;
    float* Pf  = ws;
    float* Pb  = Pf + VN * GN;
    float* Pd  = Pb + VN * GN;
    float* hf0 = Pd + VN * GN;
    float* hf1 = hf0 + BN_ * HN;
    float* hb0 = hf1 + BN_ * HN;
    float* hb1 = hb0 + BN_ * HN;
    float* hd0 = hb1 + BN_ * HN;
    float* hd1 = hd0 + BN_ * HN;

    // zero initial encoder states (hf0,hf1,hb0,hb1 are contiguous)
    zero_kernel<<<(4 * BN_ * HN + 255) / 256, 256, 0, stream>>>(hf0, 4 * BN_ * HN);
    // P tables: emb @ W + b_input
    precomp_P<<<3 * VN, 256, 0, stream>>>(src_emb, tgt_emb, Wf, bf, Wb, bb, Wd, bd, Pf, Pb, Pd);

    // encoder: both directions per launch
    for (int t = 0; t < SN; t++) {
        const float* hfi = (t & 1) ? hf1 : hf0; float* hfo = (t & 1) ? hf0 : hf1;
        const float* hbi = (t & 1) ? hb1 : hb0; float* hbo = (t & 1) ? hb0 : hb1;
        gru_step<<<dim3(BN_ / 64, HN / 64, 2), 256, 0, stream>>>(
            hfi, hfo, Uf, bf + GN, Pf, 0,
            hbi, hbo, Ub, bb + GN, Pb, 1,
            source, t);
    }
    // states = hf_T + hb_T  (final states land in buffer 0 after 24 steps)
    add_kernel<<<(BN_ * HN + 255) / 256, 256, 0, stream>>>(hf0, hb0, hd0, BN_ * HN);

    // decoder + per-step logits
    for (int t = 0; t < TN; t++) {
        const float* hdi = (t & 1) ? hd1 : hd0; float* hdo = (t & 1) ? hd0 : hd1;
        gru_step<<<dim3(BN_ / 64, HN / 64, 1), 256, 0, stream>>>(
            hdi, hdo, Ud, bd + GN, Pd, 2,
            nullptr, nullptr, nullptr, nullptr, nullptr, 0,
            targets, t);
        logits_kernel<<<dim3(BN_ / 64, VN / 64), 256, 0, stream>>>(hdo, Wo, bo, out, t);
    }
}

// Round 2
// 4015.844 us; speedup vs baseline: 1.7210x; 1.7210x over previous
//
#include <hip/hip_runtime.h>
#include <math.h>

typedef unsigned short ushort_t;
typedef short bf16x8 __attribute__((ext_vector_type(8)));   // 8 bf16 = 4 VGPRs (MFMA A/B frag)
typedef float f32x4 __attribute__((ext_vector_type(4)));    // MFMA C/D frag

#define BN_ 4096
#define SN 24
#define TN 24
#define EN 128
#define HN 512
#define GN 1536
#define VN 256
#define BOW_ 1
#define KX 1536   // extended K: [Ahi@Uhi | Alo@Uhi | Ahi@Ulo]
#define HC 1024   // hcat row stride: [hi(512) | lo(512)]

__device__ __forceinline__ float bf2f(ushort_t u) {
    union { unsigned int i; float f; } v; v.i = ((unsigned int)u) << 16; return v.f;
}
__device__ __forceinline__ ushort_t f2bf(float f) {  // round-to-nearest-even
    union { float f; unsigned int i; } v; v.f = f;
    unsigned int r = (v.i + 0x7FFFu + ((v.i >> 16) & 1u)) >> 16;
    return (ushort_t)r;
}

__global__ void zero_kernel(float4* __restrict__ p, int n16) {
    int i = blockIdx.x * blockDim.x + threadIdx.x;
    if (i < n16) p[i] = make_float4(0.f, 0.f, 0.f, 0.f);
}

// P[mat] = emb @ W + b_input  for (Wf,src), (Wb,src), (Wd,tgt). One block per (mat,row).
__global__ void precomp_P(const float* __restrict__ src_emb, const float* __restrict__ tgt_emb,
                          const float* __restrict__ Wf, const float* __restrict__ bf,
                          const float* __restrict__ Wb, const float* __restrict__ bb,
                          const float* __restrict__ Wd, const float* __restrict__ bd,
                          float* __restrict__ Pf, float* __restrict__ Pb, float* __restrict__ Pd) {
    int mat = blockIdx.x / VN;
    int row = blockIdx.x % VN;
    const float* emb = (mat == 2) ? tgt_emb : src_emb;
    const float* W   = (mat == 0) ? Wf : (mat == 1) ? Wb : Wd;
    const float* bia = (mat == 0) ? bf : (mat == 1) ? bb : bd;
    float* P         = (mat == 0) ? Pf : (mat == 1) ? Pb : Pd;
    __shared__ float e[EN];
    for (int i = threadIdx.x; i < EN; i += blockDim.x) e[i] = emb[row * EN + i];
    __syncthreads();
    for (int c = threadIdx.x; c < GN; c += blockDim.x) {
        float s = bia[c];
#pragma unroll 8
        for (int k = 0; k < EN; k++) s += e[k] * W[k * GN + c];
        P[row * GN + c] = s;
    }
}

// B' tables for the recurrent GEMM: Bt[col][k], k in [0,1536):
//   k<512: bf16hi(U[k][col]); k<1024: bf16hi(U[k-512][col]); k>=1024: bf16lo(U[k-1024][col])
__global__ void precomp_Bt(const float* __restrict__ Uf, const float* __restrict__ Ub,
                           const float* __restrict__ Ud,
                           ushort_t* __restrict__ BtF, ushort_t* __restrict__ BtB,
                           ushort_t* __restrict__ BtD) {
    int mat = blockIdx.x / GN;
    int col = blockIdx.x % GN;
    const float* U = (mat == 0) ? Uf : (mat == 1) ? Ub : Ud;
    ushort_t* Bt   = (mat == 0) ? BtF : (mat == 1) ? BtB : BtD;
    for (int k = threadIdx.x; k < KX; k += blockDim.x) {
        int ke = (k < HN) ? k : (k < 2 * HN) ? (k - HN) : (k - 2 * HN);
        float u = U[ke * GN + col];
        ushort_t hi = f2bf(u);
        Bt[(size_t)col * KX + k] = (k >= 2 * HN) ? f2bf(u - bf2f(hi)) : hi;
    }
}

__global__ void precomp_Wot(const float* __restrict__ Wo, ushort_t* __restrict__ Wot) {
    int col = blockIdx.x;  // 0..255
    for (int k = threadIdx.x; k < KX; k += blockDim.x) {
        int ke = (k < HN) ? k : (k < 2 * HN) ? (k - HN) : (k - 2 * HN);
        float u = Wo[ke * VN + col];
        ushort_t hi = f2bf(u);
        Wot[(size_t)col * KX + k] = (k >= 2 * HN) ? f2bf(u - bf2f(hi)) : hi;
    }
}

// decoder init state = hf_final + hb_final, stored as hi/lo bf16 pair
__global__ void dec_init(const ushort_t* __restrict__ hf, const ushort_t* __restrict__ hb,
                         ushort_t* __restrict__ hd) {
    int i = blockIdx.x * blockDim.x + threadIdx.x;
    if (i >= BN_ * HN) return;
    int row = i >> 9, col = i & (HN - 1);
    float h = bf2f(hf[(size_t)row * HC + col]) + bf2f(hf[(size_t)row * HC + HN + col])
            + bf2f(hb[(size_t)row * HC + col]) + bf2f(hb[(size_t)row * HC + HN + col]);
    ushort_t hi = f2bf(h);
    hd[(size_t)row * HC + col] = hi;
    hd[(size_t)row * HC + HN + col] = f2bf(h - bf2f(hi));
}

// One GRU step via bf16 MFMA split GEMM. Block: 128 rows x 64 cols (x3 gates).
// 4 waves: (wr,wc) -> 64 rows x 32 cols per gate. K-loop: 48 chunks of 32 (KX=1536).
// mode: 0 enc-fwd, 1 enc-bwd, 2 dec. blockIdx.z picks param set A/B.
__global__ __launch_bounds__(256) void gru_step(
    const ushort_t* __restrict__ hA_in, ushort_t* __restrict__ hA_out,
    const ushort_t* __restrict__ BtA, const float* __restrict__ brA,
    const float* __restrict__ PA, int modeA,
    const ushort_t* __restrict__ hB_in, ushort_t* __restrict__ hB_out,
    const ushort_t* __restrict__ BtB, const float* __restrict__ brB,
    const float* __restrict__ PB, int modeB,
    const int* __restrict__ tok, int t) {
    const ushort_t* hin; ushort_t* hout; const ushort_t* Bt; const float* brec; const float* P; int mode;
    if (blockIdx.z == 0) { hin = hA_in; hout = hA_out; Bt = BtA; brec = brA; P = PA; mode = modeA; }
    else                 { hin = hB_in; hout = hB_out; Bt = BtB; brec = brB; P = PB; mode = modeB; }

    const int bm = blockIdx.x * 128;
    const int bj = blockIdx.y * 64;
    const int tid = threadIdx.x;
    const int lane = tid & 63;
    const int w = tid >> 6;
    const int wr = w >> 1, wc = w & 1;

    // 80B padded rows: rows 0..7 span all 32 banks; 2-way (free) conflicts only
    __shared__ __align__(16) short As[128 * 40];
    __shared__ __align__(16) short Bs[192 * 40];

    f32x4 acc[3][4][2];
#pragma unroll
    for (int g = 0; g < 3; g++)
#pragma unroll
        for (int i = 0; i < 4; i++)
#pragma unroll
            for (int n = 0; n < 2; n++) acc[g][i][n] = (f32x4){0.f, 0.f, 0.f, 0.f};

    const int arow = tid >> 2;        // 0..63
    const int ak8 = (tid & 3) * 8;    // 0,8,16,24
    const ushort_t* aB0 = hin + (size_t)(bm + arow) * HC + ak8;
    const ushort_t* bB0 = Bt + (size_t)(bj + arow) * KX + ak8;  // gate g adds g*512*KX
    const int fl = lane & 15;
    const int fke = (lane >> 4) * 8;

    for (int kc = 0; kc < 48; kc++) {
        const int gk = kc * 32;
        const int agk = (gk >= 2 * HN) ? (gk - 2 * HN) : gk;  // A reuses hi for term 3
        bf16x8 av0 = *(const bf16x8*)(aB0 + agk);
        bf16x8 av1 = *(const bf16x8*)(aB0 + (size_t)64 * HC + agk);
        bf16x8 bv0 = *(const bf16x8*)(bB0 + gk);
        bf16x8 bv1 = *(const bf16x8*)(bB0 + (size_t)HN * KX + gk);
        bf16x8 bv2 = *(const bf16x8*)(bB0 + (size_t)2 * HN * KX + gk);
        __syncthreads();
        *(bf16x8*)&As[arow * 40 + ak8] = av0;
        *(bf16x8*)&As[(arow + 64) * 40 + ak8] = av1;
        *(bf16x8*)&Bs[arow * 40 + ak8] = bv0;
        *(bf16x8*)&Bs[(64 + arow) * 40 + ak8] = bv1;
        *(bf16x8*)&Bs[(128 + arow) * 40 + ak8] = bv2;
        __syncthreads();
        bf16x8 af[4];
#pragma unroll
        for (int i = 0; i < 4; i++)
            af[i] = *(const bf16x8*)&As[(wr * 64 + i * 16 + fl) * 40 + fke];
#pragma unroll
        for (int g = 0; g < 3; g++) {
            bf16x8 bf0 = *(const bf16x8*)&Bs[(g * 64 + wc * 32 + fl) * 40 + fke];
            bf16x8 bf1 = *(const bf16x8*)&Bs[(g * 64 + wc * 32 + 16 + fl) * 40 + fke];
#pragma unroll
            for (int i = 0; i < 4; i++) {
                acc[g][i][0] = __builtin_amdgcn_mfma_f32_16x16x32_bf16(af[i], bf0, acc[g][i][0], 0, 0, 0);
                acc[g][i][1] = __builtin_amdgcn_mfma_f32_16x16x32_bf16(af[i], bf1, acc[g][i][1], 0, 0, 0);
            }
        }
    }

    const int fq = lane >> 4;
#pragma unroll
    for (int i = 0; i < 4; i++) {
#pragma unroll
        for (int q = 0; q < 4; q++) {
            const int row = bm + wr * 64 + i * 16 + fq * 4 + q;
            int idx;
            if (mode == 2) idx = (t == 0) ? BOW_ : tok[row * TN + (t - 1)];
            else           idx = tok[row * SN + ((mode == 0) ? t : (SN - 1 - t))];
            const float* Pr = P + (size_t)idx * GN;
#pragma unroll
            for (int n = 0; n < 2; n++) {
                const int col = bj + wc * 32 + n * 16 + fl;
                float rz = acc[0][i][n][q] + brec[col];
                float rr = acc[1][i][n][q] + brec[HN + col];
                float rh = acc[2][i][n][q] + brec[2 * HN + col];
                float z = 1.f / (1.f + expf(-(Pr[col] + rz)));
                float r = 1.f / (1.f + expf(-(Pr[HN + col] + rr)));
                float hh = tanhf(Pr[2 * HN + col] + r * rh);
                float ho = bf2f(hin[(size_t)row * HC + col]) + bf2f(hin[(size_t)row * HC + HN + col]);
                float hnew = z * ho + (1.f - z) * hh;
                ushort_t hib = f2bf(hnew);
                hout[(size_t)row * HC + col] = hib;
                hout[(size_t)row * HC + HN + col] = f2bf(hnew - bf2f(hib));
            }
        }
    }
}

// logits[:, t, :] = hd @ Wo + bo via split GEMM. M=4096, N=256, K=1536(split).
__global__ __launch_bounds__(256) void logits_mfma(
    const ushort_t* __restrict__ hin, const ushort_t* __restrict__ Wot,
    const float* __restrict__ bo, float* __restrict__ out, int t) {
    const int bm = blockIdx.x * 128;
    const int bn = blockIdx.y * 64;
    const int tid = threadIdx.x;
    const int lane = tid & 63;
    const int w = tid >> 6;
    const int wr = w >> 1, wc = w & 1;

    __shared__ __align__(16) short As[128 * 40];
    __shared__ __align__(16) short Bs[64 * 40];

    f32x4 acc[4][2];
#pragma unroll
    for (int i = 0; i < 4; i++)
#pragma unroll
        for (int n = 0; n < 2; n++) acc[i][n] = (f32x4){0.f, 0.f, 0.f, 0.f};

    const int arow = tid >> 2;
    const int ak8 = (tid & 3) * 8;
    const ushort_t* aB0 = hin + (size_t)(bm + arow) * HC + ak8;
    const ushort_t* bB0 = Wot + (size_t)(bn + arow) * KX + ak8;
    const int fl = lane & 15;
    const int fke = (lane >> 4) * 8;

    for (int kc = 0; kc < 48; kc++) {
        const int gk = kc * 32;
        const int agk = (gk >= 2 * HN) ? (gk - 2 * HN) : gk;
        bf16x8 av0 = *(const bf16x8*)(aB0 + agk);
        bf16x8 av1 = *(const bf16x8*)(aB0 + (size_t)64 * HC + agk);
        bf16x8 bv0 = *(const bf16x8*)(bB0 + gk);
        __syncthreads();
        *(bf16x8*)&As[arow * 40 + ak8] = av0;
        *(bf16x8*)&As[(arow + 64) * 40 + ak8] = av1;
        *(bf16x8*)&Bs[arow * 40 + ak8] = bv0;
        __syncthreads();
        bf16x8 af[4];
#pragma unroll
        for (int i = 0; i < 4; i++)
            af[i] = *(const bf16x8*)&As[(wr * 64 + i * 16 + fl) * 40 + fke];
        bf16x8 bf0 = *(const bf16x8*)&Bs[(wc * 32 + fl) * 40 + fke];
        bf16x8 bf1 = *(const bf16x8*)&Bs[(wc * 32 + 16 + fl) * 40 + fke];
#pragma unroll
        for (int i = 0; i < 4; i++) {
            acc[i][0] = __builtin_amdgcn_mfma_f32_16x16x32_bf16(af[i], bf0, acc[i][0], 0, 0, 0);
            acc[i][1] = __builtin_amdgcn_mfma_f32_16x16x32_bf16(af[i], bf1, acc[i][1], 0, 0, 0);
        }
    }

    const int fq = lane >> 4;
#pragma unroll
    for (int i = 0; i < 4; i++) {
#pragma unroll
        for (int q = 0; q < 4; q++) {
            const int row = bm + wr * 64 + i * 16 + fq * 4 + q;
#pragma unroll
            for (int n = 0; n < 2; n++) {
                const int col = bn + wc * 32 + n * 16 + fl;
                out[(size_t)row * (TN * VN) + t * VN + col] = acc[i][n][q] + bo[col];
            }
        }
    }
}

extern "C" void kernel_launch(void* const* d_in, const int* in_sizes, int n_in,
                              void* d_out, int out_size, void* d_ws, size_t ws_size,
                              hipStream_t stream) {
    const int* source    = (const int*)d_in[0];
    const int* targets   = (const int*)d_in[1];
    const float* src_emb = (const float*)d_in[2];
    const float* tgt_emb = (const float*)d_in[3];
    const float* Wf = (const float*)d_in[4];
    const float* Uf = (const float*)d_in[5];
    const float* bf = (const float*)d_in[6];
    const float* Wb = (const float*)d_in[7];
    const float* Ub = (const float*)d_in[8];
    const float* bb = (const float*)d_in[9];
    const float* Wd = (const float*)d_in[10];
    const float* Ud = (const float*)d_in[11];
    const float* bd = (const float*)d_in[12];
    const float* Wo = (const float*)d_in[13];
    const float* bo = (const float*)d_in[14];
    float* out = (float*)d_out;

    char* ws = (char*)d_ws;
    ushort_t* BtF = (ushort_t*)(ws);                              // 1536*1536*2 = 4718592
    ushort_t* BtB = (ushort_t*)(ws + 4718592);
    ushort_t* BtD = (ushort_t*)(ws + 2 * 4718592);
    ushort_t* Wot = (ushort_t*)(ws + 3 * 4718592);                // 256*1536*2 = 786432
    float*    Pf  = (float*)   (ws + 3 * 4718592 + 786432);       // 3*256*1536*4 = 4718592
    float*    Pb  = Pf + VN * GN;
    float*    Pd  = Pb + VN * GN;
    char* hbase = ws + 4 * 4718592 + 786432;                      // 4 x 4096*1024*2 = 4 x 8388608
    ushort_t* hf0 = (ushort_t*)(hbase);
    ushort_t* hf1 = (ushort_t*)(hbase + 8388608);
    ushort_t* hb0 = (ushort_t*)(hbase + 2 * 8388608);
    ushort_t* hb1 = (ushort_t*)(hbase + 3 * 8388608);

    // zero all 4 h buffers (33.5 MB)
    zero_kernel<<<8192, 256, 0, stream>>>((float4*)hbase, 2097152);
    precomp_P<<<3 * VN, 256, 0, stream>>>(src_emb, tgt_emb, Wf, bf, Wb, bb, Wd, bd, Pf, Pb, Pd);
    precomp_Bt<<<3 * GN, 256, 0, stream>>>(Uf, Ub, Ud, BtF, BtB, BtD);
    precomp_Wot<<<VN, 256, 0, stream>>>(Wo, Wot);

    // encoder: both directions per launch
    for (int t = 0; t < SN; t++) {
        const ushort_t* hfi = (t & 1) ? hf1 : hf0; ushort_t* hfo = (t & 1) ? hf0 : hf1;
        const ushort_t* hbi = (t & 1) ? hb1 : hb0; ushort_t* hbo = (t & 1) ? hb0 : hb1;
        gru_step<<<dim3(BN_ / 128, HN / 64, 2), 256, 0, stream>>>(
            hfi, hfo, BtF, bf + GN, Pf, 0,
            hbi, hbo, BtB, bb + GN, Pb, 1,
            source, t);
    }
    // decoder init state into hb1 (free after encoder; finals are in hf0/hb0)
    dec_init<<<(BN_ * HN + 255) / 256, 256, 0, stream>>>(hf0, hb0, hb1);

    // decoder + per-step logits (ping-pong hb1 <-> hf1)
    for (int t = 0; t < TN; t++) {
        const ushort_t* hdi = (t & 1) ? hf1 : hb1; ushort_t* hdo = (t & 1) ? hb1 : hf1;
        gru_step<<<dim3(BN_ / 128, HN / 64, 1), 256, 0, stream>>>(
            hdi, hdo, BtD, bd + GN, Pd, 2,
            nullptr, nullptr, nullptr, nullptr, nullptr, 0,
            targets, t);
        logits_mfma<<<dim3(BN_ / 128, VN / 64), 256, 0, stream>>>(hdo, Wot, bo, out, t);
    }
}

// Round 3
// 3457.599 us; speedup vs baseline: 1.9989x; 1.1615x over previous
//
#include <hip/hip_runtime.h>
#include <math.h>

typedef unsigned short ushort_t;
typedef short bf16x8 __attribute__((ext_vector_type(8)));   // 8 bf16 = 4 VGPRs (MFMA A/B frag)
typedef float f32x4 __attribute__((ext_vector_type(4)));    // MFMA C/D frag

#define BN_ 4096
#define SN 24
#define TN 24
#define EN 128
#define HN 512
#define GN 1536
#define VN 256
#define BOW_ 1
#define KX 1536   // extended K: [Ahi@Uhi | Alo@Uhi | Ahi@Ulo]
#define HC 1024   // hcat row stride: [hi(512) | lo(512)]

__device__ __forceinline__ float bf2f(ushort_t u) {
    union { unsigned int i; float f; } v; v.i = ((unsigned int)u) << 16; return v.f;
}
__device__ __forceinline__ ushort_t f2bf(float f) {  // round-to-nearest-even
    union { float f; unsigned int i; } v; v.f = f;
    unsigned int r = (v.i + 0x7FFFu + ((v.i >> 16) & 1u)) >> 16;
    return (ushort_t)r;
}

// async global->LDS, 16B per lane. LDS dest = wave-uniform base + lane*16 (HW).
__device__ __forceinline__ void gload16(const void* g, void* l) {
    __builtin_amdgcn_global_load_lds(
        (const __attribute__((address_space(1))) unsigned int*)g,
        (__attribute__((address_space(3))) unsigned int*)l, 16, 0, 0);
}

__global__ void zero_kernel(float4* __restrict__ p, int n16) {
    int i = blockIdx.x * blockDim.x + threadIdx.x;
    if (i < n16) p[i] = make_float4(0.f, 0.f, 0.f, 0.f);
}

// P[mat] = emb @ W + b_input  for (Wf,src), (Wb,src), (Wd,tgt). One block per (mat,row).
__global__ void precomp_P(const float* __restrict__ src_emb, const float* __restrict__ tgt_emb,
                          const float* __restrict__ Wf, const float* __restrict__ bf,
                          const float* __restrict__ Wb, const float* __restrict__ bb,
                          const float* __restrict__ Wd, const float* __restrict__ bd,
                          float* __restrict__ Pf, float* __restrict__ Pb, float* __restrict__ Pd) {
    int mat = blockIdx.x / VN;
    int row = blockIdx.x % VN;
    const float* emb = (mat == 2) ? tgt_emb : src_emb;
    const float* W   = (mat == 0) ? Wf : (mat == 1) ? Wb : Wd;
    const float* bia = (mat == 0) ? bf : (mat == 1) ? bb : bd;
    float* P         = (mat == 0) ? Pf : (mat == 1) ? Pb : Pd;
    __shared__ float e[EN];
    for (int i = threadIdx.x; i < EN; i += blockDim.x) e[i] = emb[row * EN + i];
    __syncthreads();
    for (int c = threadIdx.x; c < GN; c += blockDim.x) {
        float s = bia[c];
#pragma unroll 8
        for (int k = 0; k < EN; k++) s += e[k] * W[k * GN + c];
        P[row * GN + c] = s;
    }
}

// B' tables for the recurrent GEMM: Bt[col][k], k in [0,1536):
//   k<512: bf16hi(U[k][col]); k<1024: bf16hi(U[k-512][col]); k>=1024: bf16lo(U[k-1024][col])
__global__ void precomp_Bt(const float* __restrict__ Uf, const float* __restrict__ Ub,
                           const float* __restrict__ Ud,
                           ushort_t* __restrict__ BtF, ushort_t* __restrict__ BtB,
                           ushort_t* __restrict__ BtD) {
    int mat = blockIdx.x / GN;
    int col = blockIdx.x % GN;
    const float* U = (mat == 0) ? Uf : (mat == 1) ? Ub : Ud;
    ushort_t* Bt   = (mat == 0) ? BtF : (mat == 1) ? BtB : BtD;
    for (int k = threadIdx.x; k < KX; k += blockDim.x) {
        int ke = (k < HN) ? k : (k < 2 * HN) ? (k - HN) : (k - 2 * HN);
        float u = U[ke * GN + col];
        ushort_t hi = f2bf(u);
        Bt[(size_t)col * KX + k] = (k >= 2 * HN) ? f2bf(u - bf2f(hi)) : hi;
    }
}

__global__ void precomp_Wot(const float* __restrict__ Wo, ushort_t* __restrict__ Wot) {
    int col = blockIdx.x;  // 0..255
    for (int k = threadIdx.x; k < KX; k += blockDim.x) {
        int ke = (k < HN) ? k : (k < 2 * HN) ? (k - HN) : (k - 2 * HN);
        float u = Wo[ke * VN + col];
        ushort_t hi = f2bf(u);
        Wot[(size_t)col * KX + k] = (k >= 2 * HN) ? f2bf(u - bf2f(hi)) : hi;
    }
}

// decoder init state = hf_final + hb_final, stored as hi/lo bf16 pair
__global__ void dec_init(const ushort_t* __restrict__ hf, const ushort_t* __restrict__ hb,
                         ushort_t* __restrict__ hd) {
    int i = blockIdx.x * blockDim.x + threadIdx.x;
    if (i >= BN_ * HN) return;
    int row = i >> 9, col = i & (HN - 1);
    float h = bf2f(hf[(size_t)row * HC + col]) + bf2f(hf[(size_t)row * HC + HN + col])
            + bf2f(hb[(size_t)row * HC + col]) + bf2f(hb[(size_t)row * HC + HN + col]);
    ushort_t hi = f2bf(h);
    hd[(size_t)row * HC + col] = hi;
    hd[(size_t)row * HC + HN + col] = f2bf(h - bf2f(hi));
}

// One GRU step via bf16 MFMA split GEMM.
// MT = row tile (128 enc / 64 dec), WR x WC = wave grid (WR*WC == 4), 256 threads.
// Wave tile: 64 rows x (64/WC cols) x 3 gates. K-loop: 48 chunks of 32 (KX=1536).
// Staging: global_load_lds(16B) into linear [row][32] LDS (64B rows, conflict-free),
// 2-phase double buffer, one vmcnt(0)+barrier per chunk.
template<int MT, int WR, int WC>
__global__ __launch_bounds__(256) void gru_step(
    const ushort_t* __restrict__ hA_in, ushort_t* __restrict__ hA_out,
    const ushort_t* __restrict__ BtA, const float* __restrict__ brA,
    const float* __restrict__ PA, int modeA,
    const ushort_t* __restrict__ hB_in, ushort_t* __restrict__ hB_out,
    const ushort_t* __restrict__ BtB, const float* __restrict__ brB,
    const float* __restrict__ PB, int modeB,
    const int* __restrict__ tok, int t) {
    const ushort_t* hin; ushort_t* hout; const ushort_t* Bt; const float* brec; const float* P; int mode;
    if (blockIdx.z == 0) { hin = hA_in; hout = hA_out; Bt = BtA; brec = brA; P = PA; mode = modeA; }
    else                 { hin = hB_in; hout = hB_out; Bt = BtB; brec = brB; P = PB; mode = modeB; }

    constexpr int NN = 64 / WC / 16;   // 16-col fragments per wave (2 enc, 1 dec)
    const int bm = blockIdx.x * MT;
    const int bj = blockIdx.y * 64;
    const int tid = threadIdx.x;
    const int lane = tid & 63;
    const int w = tid >> 6;
    const int wr = (WR == 1) ? 0 : (w / WC);
    const int wc = (WR == 1) ? w : (w % WC);

    __shared__ __align__(16) short Asm[2][MT * 32];
    __shared__ __align__(16) short Bsm[2][192 * 32];

    f32x4 acc[3][4][NN];
#pragma unroll
    for (int g = 0; g < 3; g++)
#pragma unroll
        for (int i = 0; i < 4; i++)
#pragma unroll
            for (int n = 0; n < NN; n++) acc[g][i][n] = (f32x4){0.f, 0.f, 0.f, 0.f};

    const int fl = lane & 15;
    const int fke = (lane >> 4) * 8;
    const int lr = lane >> 2;          // staging: row within 16-row group
    const int lk = (lane & 3) * 8;     // staging: k offset (shorts)

    auto stage = [&](int buf, int kc) {
        const int gk = kc * 32;
        const int agk = (gk >= 2 * HN) ? (gk - 2 * HN) : gk;  // A reuses hi for term 3
#pragma unroll
        for (int s = 0; s < MT / 64; ++s) {
            const int r0 = w * (MT / 4) + s * 16;
            gload16(hin + (size_t)(bm + r0 + lr) * HC + agk + lk, &Asm[buf][r0 * 32]);
        }
#pragma unroll
        for (int s = 0; s < 3; ++s) {
            const int r0 = w * 48 + s * 16;
            const int r = r0 + lr;
            gload16(Bt + (size_t)((r >> 6) * HN + bj + (r & 63)) * KX + gk + lk,
                    &Bsm[buf][r0 * 32]);
        }
    };

    stage(0, 0);
    asm volatile("s_waitcnt vmcnt(0)" ::: "memory");
    __syncthreads();

#pragma unroll 2
    for (int kc = 0; kc < 48; ++kc) {
        const int cur = kc & 1;
        if (kc < 47) stage(cur ^ 1, kc + 1);
        const short* Ab = Asm[cur];
        const short* Bb = Bsm[cur];
        bf16x8 af[4];
#pragma unroll
        for (int i = 0; i < 4; i++)
            af[i] = *(const bf16x8*)&Ab[(wr * 64 + i * 16 + fl) * 32 + fke];
#pragma unroll
        for (int g = 0; g < 3; g++) {
#pragma unroll
            for (int n = 0; n < NN; n++) {
                bf16x8 bfr = *(const bf16x8*)&Bb[(g * 64 + wc * (NN * 16) + n * 16 + fl) * 32 + fke];
#pragma unroll
                for (int i = 0; i < 4; i++)
                    acc[g][i][n] = __builtin_amdgcn_mfma_f32_16x16x32_bf16(af[i], bfr, acc[g][i][n], 0, 0, 0);
            }
        }
        asm volatile("s_waitcnt vmcnt(0)" ::: "memory");
        __syncthreads();
    }

    const int fq = lane >> 4;
#pragma unroll
    for (int i = 0; i < 4; i++) {
#pragma unroll
        for (int q = 0; q < 4; q++) {
            const int row = bm + wr * 64 + i * 16 + fq * 4 + q;
            int idx;
            if (mode == 2) idx = (t == 0) ? BOW_ : tok[row * TN + (t - 1)];
            else           idx = tok[row * SN + ((mode == 0) ? t : (SN - 1 - t))];
            const float* Pr = P + (size_t)idx * GN;
#pragma unroll
            for (int n = 0; n < NN; n++) {
                const int col = bj + wc * (NN * 16) + n * 16 + fl;
                float rz = acc[0][i][n][q] + brec[col];
                float rr = acc[1][i][n][q] + brec[HN + col];
                float rh = acc[2][i][n][q] + brec[2 * HN + col];
                float z = 1.f / (1.f + expf(-(Pr[col] + rz)));
                float r = 1.f / (1.f + expf(-(Pr[HN + col] + rr)));
                float hh = tanhf(Pr[2 * HN + col] + r * rh);
                float ho = bf2f(hin[(size_t)row * HC + col]) + bf2f(hin[(size_t)row * HC + HN + col]);
                float hnew = z * ho + (1.f - z) * hh;
                ushort_t hib = f2bf(hnew);
                hout[(size_t)row * HC + col] = hib;
                hout[(size_t)row * HC + HN + col] = f2bf(hnew - bf2f(hib));
            }
        }
    }
}

// logits[:, t, :] = hd @ Wo + bo via split GEMM. M=4096, N=256, K=1536(split).
// 64-row tiles, 4 waves of 64x16, same staging structure.
__global__ __launch_bounds__(256) void logits_mfma(
    const ushort_t* __restrict__ hin, const ushort_t* __restrict__ Wot,
    const float* __restrict__ bo, float* __restrict__ out, int t) {
    const int bm = blockIdx.x * 64;
    const int bn = blockIdx.y * 64;
    const int tid = threadIdx.x;
    const int lane = tid & 63;
    const int w = tid >> 6;   // wc

    __shared__ __align__(16) short Asm[2][64 * 32];
    __shared__ __align__(16) short Bsm[2][64 * 32];

    f32x4 acc[4];
#pragma unroll
    for (int i = 0; i < 4; i++) acc[i] = (f32x4){0.f, 0.f, 0.f, 0.f};

    const int fl = lane & 15;
    const int fke = (lane >> 4) * 8;
    const int lr = lane >> 2;
    const int lk = (lane & 3) * 8;

    auto stage = [&](int buf, int kc) {
        const int gk = kc * 32;
        const int agk = (gk >= 2 * HN) ? (gk - 2 * HN) : gk;
        {
            const int r0 = w * 16;
            gload16(hin + (size_t)(bm + r0 + lr) * HC + agk + lk, &Asm[buf][r0 * 32]);
            gload16(Wot + (size_t)(bn + r0 + lr) * KX + gk + lk, &Bsm[buf][r0 * 32]);
        }
    };

    stage(0, 0);
    asm volatile("s_waitcnt vmcnt(0)" ::: "memory");
    __syncthreads();

#pragma unroll 2
    for (int kc = 0; kc < 48; ++kc) {
        const int cur = kc & 1;
        if (kc < 47) stage(cur ^ 1, kc + 1);
        const short* Ab = Asm[cur];
        const short* Bb = Bsm[cur];
        bf16x8 bfr = *(const bf16x8*)&Bb[(w * 16 + fl) * 32 + fke];
#pragma unroll
        for (int i = 0; i < 4; i++) {
            bf16x8 af = *(const bf16x8*)&Ab[(i * 16 + fl) * 32 + fke];
            acc[i] = __builtin_amdgcn_mfma_f32_16x16x32_bf16(af, bfr, acc[i], 0, 0, 0);
        }
        asm volatile("s_waitcnt vmcnt(0)" ::: "memory");
        __syncthreads();
    }

    const int fq = lane >> 4;
#pragma unroll
    for (int i = 0; i < 4; i++) {
#pragma unroll
        for (int q = 0; q < 4; q++) {
            const int row = bm + i * 16 + fq * 4 + q;
            const int col = bn + w * 16 + fl;
            out[(size_t)row * (TN * VN) + t * VN + col] = acc[i][q] + bo[col];
        }
    }
}

extern "C" void kernel_launch(void* const* d_in, const int* in_sizes, int n_in,
                              void* d_out, int out_size, void* d_ws, size_t ws_size,
                              hipStream_t stream) {
    const int* source    = (const int*)d_in[0];
    const int* targets   = (const int*)d_in[1];
    const float* src_emb = (const float*)d_in[2];
    const float* tgt_emb = (const float*)d_in[3];
    const float* Wf = (const float*)d_in[4];
    const float* Uf = (const float*)d_in[5];
    const float* bf = (const float*)d_in[6];
    const float* Wb = (const float*)d_in[7];
    const float* Ub = (const float*)d_in[8];
    const float* bb = (const float*)d_in[9];
    const float* Wd = (const float*)d_in[10];
    const float* Ud = (const float*)d_in[11];
    const float* bd = (const float*)d_in[12];
    const float* Wo = (const float*)d_in[13];
    const float* bo = (const float*)d_in[14];
    float* out = (float*)d_out;

    char* ws = (char*)d_ws;
    ushort_t* BtF = (ushort_t*)(ws);                              // 1536*1536*2 = 4718592
    ushort_t* BtB = (ushort_t*)(ws + 4718592);
    ushort_t* BtD = (ushort_t*)(ws + 2 * 4718592);
    ushort_t* Wot = (ushort_t*)(ws + 3 * 4718592);                // 256*1536*2 = 786432
    float*    Pf  = (float*)   (ws + 3 * 4718592 + 786432);       // 3*256*1536*4 = 4718592
    float*    Pb  = Pf + VN * GN;
    float*    Pd  = Pb + VN * GN;
    char* hbase = ws + 4 * 4718592 + 786432;                      // 4 x 4096*1024*2 = 4 x 8388608
    ushort_t* hf0 = (ushort_t*)(hbase);
    ushort_t* hf1 = (ushort_t*)(hbase + 8388608);
    ushort_t* hb0 = (ushort_t*)(hbase + 2 * 8388608);
    ushort_t* hb1 = (ushort_t*)(hbase + 3 * 8388608);

    // zero all 4 h buffers (33.5 MB)
    zero_kernel<<<8192, 256, 0, stream>>>((float4*)hbase, 2097152);
    precomp_P<<<3 * VN, 256, 0, stream>>>(src_emb, tgt_emb, Wf, bf, Wb, bb, Wd, bd, Pf, Pb, Pd);
    precomp_Bt<<<3 * GN, 256, 0, stream>>>(Uf, Ub, Ud, BtF, BtB, BtD);
    precomp_Wot<<<VN, 256, 0, stream>>>(Wo, Wot);

    // encoder: both directions per launch; 128-row tiles, waves 2x2
    for (int t = 0; t < SN; t++) {
        const ushort_t* hfi = (t & 1) ? hf1 : hf0; ushort_t* hfo = (t & 1) ? hf0 : hf1;
        const ushort_t* hbi = (t & 1) ? hb1 : hb0; ushort_t* hbo = (t & 1) ? hb0 : hb1;
        gru_step<128, 2, 2><<<dim3(BN_ / 128, HN / 64, 2), 256, 0, stream>>>(
            hfi, hfo, BtF, bf + GN, Pf, 0,
            hbi, hbo, BtB, bb + GN, Pb, 1,
            source, t);
    }
    // decoder init state into hb1 (free after encoder; finals are in hf0/hb0)
    dec_init<<<(BN_ * HN + 255) / 256, 256, 0, stream>>>(hf0, hb0, hb1);

    // decoder + per-step logits (ping-pong hb1 <-> hf1); 64-row tiles, waves 1x4
    for (int t = 0; t < TN; t++) {
        const ushort_t* hdi = (t & 1) ? hf1 : hb1; ushort_t* hdo = (t & 1) ? hb1 : hf1;
        gru_step<64, 1, 4><<<dim3(BN_ / 64, HN / 64, 1), 256, 0, stream>>>(
            hdi, hdo, BtD, bd + GN, Pd, 2,
            nullptr, nullptr, nullptr, nullptr, nullptr, 0,
            targets, t);
        logits_mfma<<<dim3(BN_ / 64, VN / 64), 256, 0, stream>>>(hdo, Wot, bo, out, t);
    }
}

// Round 4
// 3407.416 us; speedup vs baseline: 2.0283x; 1.0147x over previous
//
#include <hip/hip_runtime.h>
#include <math.h>

typedef unsigned short ushort_t;
typedef short bf16x8 __attribute__((ext_vector_type(8)));   // 8 bf16 = 4 VGPRs (MFMA A/B frag)
typedef float f32x4 __attribute__((ext_vector_type(4)));    // MFMA C/D frag

#define BN_ 4096
#define SN 24
#define TN 24
#define EN 128
#define HN 512
#define GN 1536
#define VN 256
#define BOW_ 1
#define KX 1536   // extended K: [Ahi@Uhi | Alo@Uhi | Ahi@Ulo]
#define HC 1024   // hcat row stride: [hi(512) | lo(512)]

__device__ __forceinline__ float bf2f(ushort_t u) {
    union { unsigned int i; float f; } v; v.i = ((unsigned int)u) << 16; return v.f;
}
__device__ __forceinline__ ushort_t f2bf(float f) {  // round-to-nearest-even
    union { float f; unsigned int i; } v; v.f = f;
    unsigned int r = (v.i + 0x7FFFu + ((v.i >> 16) & 1u)) >> 16;
    return (ushort_t)r;
}

// async global->LDS, 16B per lane. LDS dest = wave-uniform base + lane*16 (HW).
__device__ __forceinline__ void gload16(const void* g, void* l) {
    __builtin_amdgcn_global_load_lds(
        (const __attribute__((address_space(1))) unsigned int*)g,
        (__attribute__((address_space(3))) unsigned int*)l, 16, 0, 0);
}

template<int N> __device__ __forceinline__ void waitcnt_vm() {
    if constexpr (N == 0) asm volatile("s_waitcnt vmcnt(0)" ::: "memory");
    else if constexpr (N == 2) asm volatile("s_waitcnt vmcnt(2)" ::: "memory");
    else if constexpr (N == 4) asm volatile("s_waitcnt vmcnt(4)" ::: "memory");
    else if constexpr (N == 5) asm volatile("s_waitcnt vmcnt(5)" ::: "memory");
    else static_assert(N == 0, "unsupported vmcnt");
}
__device__ __forceinline__ void barrier_() { asm volatile("s_barrier" ::: "memory"); }

__global__ void zero_kernel(float4* __restrict__ p, int n16) {
    int i = blockIdx.x * blockDim.x + threadIdx.x;
    if (i < n16) p[i] = make_float4(0.f, 0.f, 0.f, 0.f);
}

// P[mat] = emb @ W + b_input  for (Wf,src), (Wb,src), (Wd,tgt). One block per (mat,row).
__global__ void precomp_P(const float* __restrict__ src_emb, const float* __restrict__ tgt_emb,
                          const float* __restrict__ Wf, const float* __restrict__ bf,
                          const float* __restrict__ Wb, const float* __restrict__ bb,
                          const float* __restrict__ Wd, const float* __restrict__ bd,
                          float* __restrict__ Pf, float* __restrict__ Pb, float* __restrict__ Pd) {
    int mat = blockIdx.x / VN;
    int row = blockIdx.x % VN;
    const float* emb = (mat == 2) ? tgt_emb : src_emb;
    const float* W   = (mat == 0) ? Wf : (mat == 1) ? Wb : Wd;
    const float* bia = (mat == 0) ? bf : (mat == 1) ? bb : bd;
    float* P         = (mat == 0) ? Pf : (mat == 1) ? Pb : Pd;
    __shared__ float e[EN];
    for (int i = threadIdx.x; i < EN; i += blockDim.x) e[i] = emb[row * EN + i];
    __syncthreads();
    for (int c = threadIdx.x; c < GN; c += blockDim.x) {
        float s = bia[c];
#pragma unroll 8
        for (int k = 0; k < EN; k++) s += e[k] * W[k * GN + c];
        P[row * GN + c] = s;
    }
}

// B' tables for the recurrent GEMM: Bt[col][k], k in [0,1536):
//   k<512: bf16hi(U[k][col]); k<1024: bf16hi(U[k-512][col]); k>=1024: bf16lo(U[k-1024][col])
__global__ void precomp_Bt(const float* __restrict__ Uf, const float* __restrict__ Ub,
                           const float* __restrict__ Ud,
                           ushort_t* __restrict__ BtF, ushort_t* __restrict__ BtB,
                           ushort_t* __restrict__ BtD) {
    int mat = blockIdx.x / GN;
    int col = blockIdx.x % GN;
    const float* U = (mat == 0) ? Uf : (mat == 1) ? Ub : Ud;
    ushort_t* Bt   = (mat == 0) ? BtF : (mat == 1) ? BtB : BtD;
    for (int k = threadIdx.x; k < KX; k += blockDim.x) {
        int ke = (k < HN) ? k : (k < 2 * HN) ? (k - HN) : (k - 2 * HN);
        float u = U[ke * GN + col];
        ushort_t hi = f2bf(u);
        Bt[(size_t)col * KX + k] = (k >= 2 * HN) ? f2bf(u - bf2f(hi)) : hi;
    }
}

__global__ void precomp_Wot(const float* __restrict__ Wo, ushort_t* __restrict__ Wot) {
    int col = blockIdx.x;  // 0..255
    for (int k = threadIdx.x; k < KX; k += blockDim.x) {
        int ke = (k < HN) ? k : (k < 2 * HN) ? (k - HN) : (k - 2 * HN);
        float u = Wo[ke * VN + col];
        ushort_t hi = f2bf(u);
        Wot[(size_t)col * KX + k] = (k >= 2 * HN) ? f2bf(u - bf2f(hi)) : hi;
    }
}

// decoder init state = hf_final + hb_final, stored as hi/lo bf16 pair
__global__ void dec_init(const ushort_t* __restrict__ hf, const ushort_t* __restrict__ hb,
                         ushort_t* __restrict__ hd) {
    int i = blockIdx.x * blockDim.x + threadIdx.x;
    if (i >= BN_ * HN) return;
    int row = i >> 9, col = i & (HN - 1);
    float h = bf2f(hf[(size_t)row * HC + col]) + bf2f(hf[(size_t)row * HC + HN + col])
            + bf2f(hb[(size_t)row * HC + col]) + bf2f(hb[(size_t)row * HC + HN + col]);
    ushort_t hi = f2bf(h);
    hd[(size_t)row * HC + col] = hi;
    hd[(size_t)row * HC + HN + col] = f2bf(h - bf2f(hi));
}

// One GRU step via bf16 MFMA split GEMM.
// MT = row tile (128 enc / 64 dec), WR x WC = wave grid (WR*WC == 4), 256 threads.
// Wave tile: 64 rows x (64/WC cols) x 3 gates. K-loop: 48 chunks of 32 (KX=1536).
// Staging: global_load_lds(16B) into [row][32] LDS (64B rows) with a both-sides XOR
// swizzle: global source slot ^= row-derived bits; frag read slot ^= same bits.
// Read slot index = (lane>>4) ^ ((lane>>1)&3)  -> every ds_read_b128 covers all
// 32 banks at the 8-access minimum (conflict-free).
// Schedule: 2-phase double buffer, counted vmcnt + raw barrier pair per chunk.
template<int MT, int WR, int WC>
__global__ __launch_bounds__(256) void gru_step(
    const ushort_t* __restrict__ hA_in, ushort_t* __restrict__ hA_out,
    const ushort_t* __restrict__ BtA, const float* __restrict__ brA,
    const float* __restrict__ PA, int modeA,
    const ushort_t* __restrict__ hB_in, ushort_t* __restrict__ hB_out,
    const ushort_t* __restrict__ BtB, const float* __restrict__ brB,
    const float* __restrict__ PB, int modeB,
    const int* __restrict__ tok, int t) {
    const ushort_t* hin; ushort_t* hout; const ushort_t* Bt; const float* brec; const float* P; int mode;
    if (blockIdx.z == 0) { hin = hA_in; hout = hA_out; Bt = BtA; brec = brA; P = PA; mode = modeA; }
    else                 { hin = hB_in; hout = hB_out; Bt = BtB; brec = brB; P = PB; mode = modeB; }

    constexpr int NN = 64 / WC / 16;      // 16-col fragments per wave (2 enc, 1 dec)
    constexpr int NST = MT / 64 + 3;      // gloads issued per wave per stage
    const int bm = blockIdx.x * MT;
    const int bj = blockIdx.y * 64;
    const int tid = threadIdx.x;
    const int lane = tid & 63;
    const int w = tid >> 6;
    const int wr = (WR == 1) ? 0 : (w / WC);
    const int wc = (WR == 1) ? w : (w % WC);

    __shared__ __align__(16) short Asm[2][MT * 32];
    __shared__ __align__(16) short Bsm[2][192 * 32];

    f32x4 acc[3][4][NN];
#pragma unroll
    for (int g = 0; g < 3; g++)
#pragma unroll
        for (int i = 0; i < 4; i++)
#pragma unroll
            for (int n = 0; n < NN; n++) acc[g][i][n] = (f32x4){0.f, 0.f, 0.f, 0.f};

    const int fl = lane & 15;
    // swizzled frag-read k-offset (shorts): slot = (lane>>4) ^ ((row&15)>>1 & 3), row%16 == fl
    const int fke = (((lane >> 4) ^ ((lane >> 1) & 3)) * 8);
    const int lr = lane >> 2;                                   // staging: row within 16-row group
    const int lk = (((lane & 3) ^ ((lane >> 3) & 3)) * 8);      // staging: swizzled global slot

    auto stage = [&](int buf, int kc) {
        const int gk = kc * 32;
        const int agk = (gk >= 2 * HN) ? (gk - 2 * HN) : gk;  // A reuses hi for term 3
#pragma unroll
        for (int s = 0; s < MT / 64; ++s) {
            const int r0 = w * (MT / 4) + s * 16;
            gload16(hin + (size_t)(bm + r0 + lr) * HC + agk + lk, &Asm[buf][r0 * 32]);
        }
#pragma unroll
        for (int s = 0; s < 3; ++s) {
            const int r0 = w * 48 + s * 16;
            const int r = r0 + lr;
            gload16(Bt + (size_t)((r >> 6) * HN + bj + (r & 63)) * KX + gk + lk,
                    &Bsm[buf][r0 * 32]);
        }
    };

    stage(0, 0);

#pragma unroll 2
    for (int kc = 0; kc < 48; ++kc) {
        const int cur = kc & 1;
        if (kc < 47) { stage(cur ^ 1, kc + 1); waitcnt_vm<NST>(); }
        else         { waitcnt_vm<0>(); }
        barrier_();                       // buf[cur] ready for all waves
        const short* Ab = Asm[cur];
        const short* Bb = Bsm[cur];
        bf16x8 af[4];
#pragma unroll
        for (int i = 0; i < 4; i++)
            af[i] = *(const bf16x8*)&Ab[(wr * 64 + i * 16 + fl) * 32 + fke];
#pragma unroll
        for (int g = 0; g < 3; g++) {
#pragma unroll
            for (int n = 0; n < NN; n++) {
                bf16x8 bfr = *(const bf16x8*)&Bb[(g * 64 + wc * (NN * 16) + n * 16 + fl) * 32 + fke];
#pragma unroll
                for (int i = 0; i < 4; i++)
                    acc[g][i][n] = __builtin_amdgcn_mfma_f32_16x16x32_bf16(af[i], bfr, acc[g][i][n], 0, 0, 0);
            }
        }
        barrier_();                       // all reads of buf[cur] done -> next iter may overwrite
    }

    const int fq = lane >> 4;
#pragma unroll
    for (int i = 0; i < 4; i++) {
#pragma unroll
        for (int q = 0; q < 4; q++) {
            const int row = bm + wr * 64 + i * 16 + fq * 4 + q;
            int idx;
            if (mode == 2) idx = (t == 0) ? BOW_ : tok[row * TN + (t - 1)];
            else           idx = tok[row * SN + ((mode == 0) ? t : (SN - 1 - t))];
            const float* Pr = P + (size_t)idx * GN;
#pragma unroll
            for (int n = 0; n < NN; n++) {
                const int col = bj + wc * (NN * 16) + n * 16 + fl;
                float rz = acc[0][i][n][q] + brec[col];
                float rr = acc[1][i][n][q] + brec[HN + col];
                float rh = acc[2][i][n][q] + brec[2 * HN + col];
                float z = 1.f / (1.f + expf(-(Pr[col] + rz)));
                float r = 1.f / (1.f + expf(-(Pr[HN + col] + rr)));
                float hh = tanhf(Pr[2 * HN + col] + r * rh);
                float ho = bf2f(hin[(size_t)row * HC + col]) + bf2f(hin[(size_t)row * HC + HN + col]);
                float hnew = z * ho + (1.f - z) * hh;
                ushort_t hib = f2bf(hnew);
                hout[(size_t)row * HC + col] = hib;
                hout[(size_t)row * HC + HN + col] = f2bf(hnew - bf2f(hib));
            }
        }
    }
}

// logits[:, t, :] = hd @ Wo + bo via split GEMM. M=4096, N=256, K=1536(split).
// 64-row tiles, 4 waves of 64x16, same swizzle + schedule.
__global__ __launch_bounds__(256) void logits_mfma(
    const ushort_t* __restrict__ hin, const ushort_t* __restrict__ Wot,
    const float* __restrict__ bo, float* __restrict__ out, int t) {
    const int bm = blockIdx.x * 64;
    const int bn = blockIdx.y * 64;
    const int tid = threadIdx.x;
    const int lane = tid & 63;
    const int w = tid >> 6;   // wc

    __shared__ __align__(16) short Asm[2][64 * 32];
    __shared__ __align__(16) short Bsm[2][64 * 32];

    f32x4 acc[4];
#pragma unroll
    for (int i = 0; i < 4; i++) acc[i] = (f32x4){0.f, 0.f, 0.f, 0.f};

    const int fl = lane & 15;
    const int fke = (((lane >> 4) ^ ((lane >> 1) & 3)) * 8);
    const int lr = lane >> 2;
    const int lk = (((lane & 3) ^ ((lane >> 3) & 3)) * 8);

    auto stage = [&](int buf, int kc) {
        const int gk = kc * 32;
        const int agk = (gk >= 2 * HN) ? (gk - 2 * HN) : gk;
        const int r0 = w * 16;
        gload16(hin + (size_t)(bm + r0 + lr) * HC + agk + lk, &Asm[buf][r0 * 32]);
        gload16(Wot + (size_t)(bn + r0 + lr) * KX + gk + lk, &Bsm[buf][r0 * 32]);
    };

    stage(0, 0);

#pragma unroll 2
    for (int kc = 0; kc < 48; ++kc) {
        const int cur = kc & 1;
        if (kc < 47) { stage(cur ^ 1, kc + 1); waitcnt_vm<2>(); }
        else         { waitcnt_vm<0>(); }
        barrier_();
        const short* Ab = Asm[cur];
        const short* Bb = Bsm[cur];
        bf16x8 bfr = *(const bf16x8*)&Bb[(w * 16 + fl) * 32 + fke];
#pragma unroll
        for (int i = 0; i < 4; i++) {
            bf16x8 af = *(const bf16x8*)&Ab[(i * 16 + fl) * 32 + fke];
            acc[i] = __builtin_amdgcn_mfma_f32_16x16x32_bf16(af, bfr, acc[i], 0, 0, 0);
        }
        barrier_();
    }

    const int fq = lane >> 4;
#pragma unroll
    for (int i = 0; i < 4; i++) {
#pragma unroll
        for (int q = 0; q < 4; q++) {
            const int row = bm + i * 16 + fq * 4 + q;
            const int col = bn + w * 16 + fl;
            out[(size_t)row * (TN * VN) + t * VN + col] = acc[i][q] + bo[col];
        }
    }
}

extern "C" void kernel_launch(void* const* d_in, const int* in_sizes, int n_in,
                              void* d_out, int out_size, void* d_ws, size_t ws_size,
                              hipStream_t stream) {
    const int* source    = (const int*)d_in[0];
    const int* targets   = (const int*)d_in[1];
    const float* src_emb = (const float*)d_in[2];
    const float* tgt_emb = (const float*)d_in[3];
    const float* Wf = (const float*)d_in[4];
    const float* Uf = (const float*)d_in[5];
    const float* bf = (const float*)d_in[6];
    const float* Wb = (const float*)d_in[7];
    const float* Ub = (const float*)d_in[8];
    const float* bb = (const float*)d_in[9];
    const float* Wd = (const float*)d_in[10];
    const float* Ud = (const float*)d_in[11];
    const float* bd = (const float*)d_in[12];
    const float* Wo = (const float*)d_in[13];
    const float* bo = (const float*)d_in[14];
    float* out = (float*)d_out;

    char* ws = (char*)d_ws;
    ushort_t* BtF = (ushort_t*)(ws);                              // 1536*1536*2 = 4718592
    ushort_t* BtB = (ushort_t*)(ws + 4718592);
    ushort_t* BtD = (ushort_t*)(ws + 2 * 4718592);
    ushort_t* Wot = (ushort_t*)(ws + 3 * 4718592);                // 256*1536*2 = 786432
    float*    Pf  = (float*)   (ws + 3 * 4718592 + 786432);       // 3*256*1536*4 = 4718592
    float*    Pb  = Pf + VN * GN;
    float*    Pd  = Pb + VN * GN;
    char* hbase = ws + 4 * 4718592 + 786432;                      // 4 x 4096*1024*2 = 4 x 8388608
    ushort_t* hf0 = (ushort_t*)(hbase);
    ushort_t* hf1 = (ushort_t*)(hbase + 8388608);
    ushort_t* hb0 = (ushort_t*)(hbase + 2 * 8388608);
    ushort_t* hb1 = (ushort_t*)(hbase + 3 * 8388608);

    // zero all 4 h buffers (33.5 MB)
    zero_kernel<<<8192, 256, 0, stream>>>((float4*)hbase, 2097152);
    precomp_P<<<3 * VN, 256, 0, stream>>>(src_emb, tgt_emb, Wf, bf, Wb, bb, Wd, bd, Pf, Pb, Pd);
    precomp_Bt<<<3 * GN, 256, 0, stream>>>(Uf, Ub, Ud, BtF, BtB, BtD);
    precomp_Wot<<<VN, 256, 0, stream>>>(Wo, Wot);

    // encoder: both directions per launch; 128-row tiles, waves 2x2
    for (int t = 0; t < SN; t++) {
        const ushort_t* hfi = (t & 1) ? hf1 : hf0; ushort_t* hfo = (t & 1) ? hf0 : hf1;
        const ushort_t* hbi = (t & 1) ? hb1 : hb0; ushort_t* hbo = (t & 1) ? hb0 : hb1;
        gru_step<128, 2, 2><<<dim3(BN_ / 128, HN / 64, 2), 256, 0, stream>>>(
            hfi, hfo, BtF, bf + GN, Pf, 0,
            hbi, hbo, BtB, bb + GN, Pb, 1,
            source, t);
    }
    // decoder init state into hb1 (free after encoder; finals are in hf0/hb0)
    dec_init<<<(BN_ * HN + 255) / 256, 256, 0, stream>>>(hf0, hb0, hb1);

    // decoder + per-step logits (ping-pong hb1 <-> hf1); 64-row tiles, waves 1x4
    for (int t = 0; t < TN; t++) {
        const ushort_t* hdi = (t & 1) ? hf1 : hb1; ushort_t* hdo = (t & 1) ? hb1 : hf1;
        gru_step<64, 1, 4><<<dim3(BN_ / 64, HN / 64, 1), 256, 0, stream>>>(
            hdi, hdo, BtD, bd + GN, Pd, 2,
            nullptr, nullptr, nullptr, nullptr, nullptr, 0,
            targets, t);
        logits_mfma<<<dim3(BN_ / 64, VN / 64), 256, 0, stream>>>(hdo, Wot, bo, out, t);
    }
}